// Round 1
// baseline (45258.868 us; speedup 1.0000x reference)
//
#include <hip/hip_runtime.h>
#include <math.h>

// B=128, E=512, D=512, V=275, HW=24 -> P=576, T=300
static constexpr int Bn  = 128;
static constexpr int En  = 512;
static constexpr int Dn  = 512;
static constexpr int Vn  = 275;
static constexpr int Pn  = 576;
static constexpr int Tn  = 300;
static constexpr int TM1 = 299;

__device__ __forceinline__ float fast_tanh(float x) {
    // 1 - 2/(e^{2x}+1): exp overflow -> inf -> 1; underflow -> 0 -> -1. No NaN.
    float e2 = __expf(2.0f * x);
    return 1.0f - 2.0f / (e2 + 1.0f);
}
__device__ __forceinline__ float sigmoidf_(float x) {
    return 1.0f / (1.0f + __expf(-x));
}
__device__ __forceinline__ float wave_reduce(float v) {
#pragma unroll
    for (int o = 32; o > 0; o >>= 1) v += __shfl_xor(v, o, 64);
    return v;
}

// ---------------- one-time kernels ----------------

// mean over P for each (b,e) row; feats is [B,E,P] contiguous.
__global__ void mean_kernel(const float* __restrict__ feats, float* __restrict__ mean) {
    int w = blockIdx.x * 4 + (threadIdx.x >> 6);   // row in [0, B*E)
    int lane = threadIdx.x & 63;
    const float* row = feats + (size_t)w * Pn;
    float s = 0.f;
#pragma unroll
    for (int i = 0; i < 9; i++) s += row[lane + i * 64];
    s = wave_reduce(s);
    if (lane == 0) mean[w] = s * (1.0f / Pn);
}

// h0 = mean@init_h_w + b ; c0 = mean@init_c_w + b
__global__ void init_kernel(const float* __restrict__ mean,
                            const float* __restrict__ ihw, const float* __restrict__ ihb,
                            const float* __restrict__ icw, const float* __restrict__ icb,
                            float* __restrict__ h, float* __restrict__ c) {
    int b = blockIdx.x; int d = threadIdx.x;  // 512 threads
    const float* m = mean + b * En;
    float ah = ihb[d], ac = icb[d];
#pragma unroll 8
    for (int e = 0; e < En; e++) {
        float mv = m[e];
        ah += mv * ihw[e * Dn + d];
        ac += mv * icw[e * Dn + d];
    }
    h[b * Dn + d] = ah;
    c[b * Dn + d] = ac;
}

// Ws[b,p,d] = sum_e feats[b,e,p] * W_w[e,d] + W_b[d]
__global__ void ws_kernel(const float* __restrict__ feats, const float* __restrict__ Ww,
                          const float* __restrict__ Wb, float* __restrict__ Ws) {
    int p = blockIdx.x, b = blockIdx.y, d = threadIdx.x;  // 512 threads
    const float* f = feats + (size_t)b * En * Pn + p;     // stride P over e
    float acc = Wb[d];
#pragma unroll 8
    for (int e = 0; e < En; e++) acc += f[(size_t)e * Pn] * Ww[e * Dn + d];
    Ws[((size_t)b * Pn + p) * Dn + d] = acc;
}

__global__ void declen_kernel(const int* __restrict__ lengths, float* __restrict__ out_declen) {
    int b = threadIdx.x;
    if (b < Bn) out_declen[b] = (float)(lengths[b] - 1);
}

// generic transpose: src[rows][cols] -> dst[cols][rows]
__global__ void transpose_kernel(const float* __restrict__ src, float* __restrict__ dst,
                                 int rows, int cols) {
    int idx = blockIdx.x * 256 + threadIdx.x;
    if (idx >= rows * cols) return;
    int r = idx / cols, c = idx - r * cols;
    dst[(size_t)c * rows + r] = src[idx];
}

// ---------------- per-step kernels ----------------

// hU[b,d] = h@U_w + U_b ; gate[b,e] = sigmoid(h@f_beta_w + f_beta_b)
// wave per (bgroup-of-4, j in [0,1024)); transposed weights (row-contiguous).
__global__ __launch_bounds__(256) void k1_kernel(
        const float* __restrict__ h, const float* __restrict__ UwT, const float* __restrict__ Ub,
        const float* __restrict__ fbwT, const float* __restrict__ fbb,
        float* __restrict__ hU, float* __restrict__ gate) {
    int w = blockIdx.x * 4 + (threadIdx.x >> 6);   // [0, 32*1024)
    int lane = threadIdx.x & 63;
    int bg = w >> 10, j = w & 1023;
    const float* row = (j < 512) ? (UwT + (size_t)j * 512) : (fbwT + (size_t)(j - 512) * 512);
    float4 hv[4][2];
#pragma unroll
    for (int i = 0; i < 4; i++) {
        const float* hb = h + (bg * 4 + i) * Dn;
        hv[i][0] = *(const float4*)(hb + 4 * lane);
        hv[i][1] = *(const float4*)(hb + 4 * lane + 256);
    }
    float acc[4] = {0.f, 0.f, 0.f, 0.f};
#pragma unroll
    for (int c = 0; c < 2; c++) {
        float4 wv = *(const float4*)(row + 4 * lane + 256 * c);
#pragma unroll
        for (int i = 0; i < 4; i++)
            acc[i] += hv[i][c].x * wv.x + hv[i][c].y * wv.y + hv[i][c].z * wv.z + hv[i][c].w * wv.w;
    }
#pragma unroll
    for (int o = 32; o > 0; o >>= 1) {
#pragma unroll
        for (int i = 0; i < 4; i++) acc[i] += __shfl_xor(acc[i], o, 64);
    }
    if (lane == 0) {
        if (j < 512) {
            float bias = Ub[j];
#pragma unroll
            for (int i = 0; i < 4; i++) hU[(bg * 4 + i) * Dn + j] = acc[i] + bias;
        } else {
            int e = j - 512;
            float bias = fbb[e];
#pragma unroll
            for (int i = 0; i < 4; i++) gate[(bg * 4 + i) * En + e] = sigmoidf_(acc[i] + bias);
        }
    }
}

// e[b,p] = sum_d tanh(Ws[b,p,d] + hU[b,d]) * v_w[d] + v_b   (wave per (b,p))
__global__ __launch_bounds__(256) void k2_kernel(
        const float* __restrict__ Ws, const float* __restrict__ hU,
        const float* __restrict__ vw, const float* __restrict__ vb,
        float* __restrict__ esc) {
    int w = blockIdx.x * 4 + (threadIdx.x >> 6);  // [0, B*P)
    int lane = threadIdx.x & 63;
    int b = w / Pn, p = w - b * Pn;
    const float4* wsr = (const float4*)(Ws + ((size_t)b * Pn + p) * Dn);
    const float4* hur = (const float4*)(hU + b * Dn);
    const float4* vwr = (const float4*)vw;
    float acc = 0.f;
#pragma unroll
    for (int j = 0; j < 2; j++) {
        int idx = lane + j * 64;
        float4 a = wsr[idx], hv = hur[idx], vv = vwr[idx];
        acc += fast_tanh(a.x + hv.x) * vv.x;
        acc += fast_tanh(a.y + hv.y) * vv.y;
        acc += fast_tanh(a.z + hv.z) * vv.z;
        acc += fast_tanh(a.w + hv.w) * vv.w;
    }
    acc = wave_reduce(acc);
    if (lane == 0) esc[w] = acc + vb[0];
}

// softmax over P per b; write alpha (unmasked, for ctx) and masked alphas output.
__global__ void k3_kernel(const float* __restrict__ esc, float* __restrict__ alpha,
                          float* __restrict__ out_alphas, const int* __restrict__ lengths, int t) {
    __shared__ float red[16];
    int b = blockIdx.x, tid = threadIdx.x;   // 576 threads
    int wid = tid >> 6, lane = tid & 63;
    float v = esc[b * Pn + tid];
    float m = v;
#pragma unroll
    for (int o = 32; o > 0; o >>= 1) m = fmaxf(m, __shfl_xor(m, o, 64));
    if (lane == 0) red[wid] = m;
    __syncthreads();
    if (tid == 0) {
        float mm = red[0];
        for (int i = 1; i < 9; i++) mm = fmaxf(mm, red[i]);
        red[9] = mm;
    }
    __syncthreads();
    float mx = red[9];
    float ex = __expf(v - mx);
    float s = ex;
#pragma unroll
    for (int o = 32; o > 0; o >>= 1) s += __shfl_xor(s, o, 64);
    if (lane == 0) red[wid] = s;
    __syncthreads();
    if (tid == 0) {
        float ss = 0.f;
        for (int i = 0; i < 9; i++) ss += red[i];
        red[10] = ss;
    }
    __syncthreads();
    float a = ex / red[10];
    alpha[b * Pn + tid] = a;
    int dec = lengths[b] - 1;
    out_alphas[((size_t)b * TM1 + t) * Pn + tid] = (t < dec) ? a : 0.f;
}

// xctx[b,e] = gate[b,e] * sum_p alpha[b,p] * feats[b,e,p]   (wave per (b,e))
__global__ __launch_bounds__(256) void k4_kernel(
        const float* __restrict__ feats, const float* __restrict__ alpha,
        const float* __restrict__ gate, float* __restrict__ xctx) {
    int w = blockIdx.x * 4 + (threadIdx.x >> 6);  // [0, B*E)
    int lane = threadIdx.x & 63;
    int b = w >> 9;
    const float* f = feats + (size_t)w * Pn;
    const float* al = alpha + b * Pn;
    float s = 0.f;
#pragma unroll
    for (int i = 0; i < 9; i++) {
        int p = lane + i * 64;
        s += al[p] * f[p];
    }
    s = wave_reduce(s);
    if (lane == 0) xctx[w] = gate[w] * s;
}

// LSTM gate pre-activations: g[b,j] = xin@w_ih[j,:] + h@w_hh[j,:] + b_ih[j] + b_hh[j]
// xin = [emb[captions[b,t]] (512) | xctx[b] (512)].  Wave per (bgroup-of-4, j in [0,2048)).
__global__ __launch_bounds__(256) void k5_kernel(
        const float* __restrict__ h, const float* __restrict__ xctx,
        const float* __restrict__ emb, const int* __restrict__ captions,
        const float* __restrict__ wih, const float* __restrict__ whh,
        const float* __restrict__ bih, const float* __restrict__ bhh,
        float* __restrict__ g, int t) {
    int w = blockIdx.x * 4 + (threadIdx.x >> 6);  // [0, 32*2048)
    int lane = threadIdx.x & 63;
    int bg = w >> 11, j = w & 2047;
    float4 u[4][4];   // xin chunks: c -> k = 4*lane + 256*c
    float4 hr[4][2];
#pragma unroll
    for (int i = 0; i < 4; i++) {
        int b = bg * 4 + i;
        const float* et = emb + (size_t)captions[b * Tn + t] * Dn;
        const float* xc = xctx + b * En;
        const float* hb = h + b * Dn;
        u[i][0] = *(const float4*)(et + 4 * lane);
        u[i][1] = *(const float4*)(et + 4 * lane + 256);
        u[i][2] = *(const float4*)(xc + 4 * lane);
        u[i][3] = *(const float4*)(xc + 4 * lane + 256);
        hr[i][0] = *(const float4*)(hb + 4 * lane);
        hr[i][1] = *(const float4*)(hb + 4 * lane + 256);
    }
    const float* wi = wih + (size_t)j * (Dn + En);
    const float* wh = whh + (size_t)j * Dn;
    float acc[4] = {0.f, 0.f, 0.f, 0.f};
#pragma unroll
    for (int c = 0; c < 4; c++) {
        float4 wv = *(const float4*)(wi + 4 * lane + 256 * c);
#pragma unroll
        for (int i = 0; i < 4; i++)
            acc[i] += u[i][c].x * wv.x + u[i][c].y * wv.y + u[i][c].z * wv.z + u[i][c].w * wv.w;
    }
#pragma unroll
    for (int c = 0; c < 2; c++) {
        float4 wv = *(const float4*)(wh + 4 * lane + 256 * c);
#pragma unroll
        for (int i = 0; i < 4; i++)
            acc[i] += hr[i][c].x * wv.x + hr[i][c].y * wv.y + hr[i][c].z * wv.z + hr[i][c].w * wv.w;
    }
#pragma unroll
    for (int o = 32; o > 0; o >>= 1) {
#pragma unroll
        for (int i = 0; i < 4; i++) acc[i] += __shfl_xor(acc[i], o, 64);
    }
    if (lane == 0) {
        float bias = bih[j] + bhh[j];
#pragma unroll
        for (int i = 0; i < 4; i++) g[(size_t)(bg * 4 + i) * (4 * Dn) + j] = acc[i] + bias;
    }
}

// LSTM pointwise: torch gate order i,f,g,o at rows d, D+d, 2D+d, 3D+d
__global__ void k5b_kernel(const float* __restrict__ g, float* __restrict__ h2,
                           float* __restrict__ c) {
    int idx = blockIdx.x * 256 + threadIdx.x;  // [0, B*D)
    int b = idx >> 9, d = idx & 511;
    const float* gb = g + (size_t)b * (4 * Dn);
    float ig = sigmoidf_(gb[d]);
    float fg = sigmoidf_(gb[Dn + d]);
    float gg = fast_tanh(gb[2 * Dn + d]);
    float og = sigmoidf_(gb[3 * Dn + d]);
    float cn = fg * c[idx] + ig * gg;
    c[idx] = cn;
    h2[idx] = og * fast_tanh(cn);
}

// pred[b,v] = h2@fc_w[:,v] + fc_b[v], masked.  fcwT is [V][D]; wave per (bgroup-of-4, v).
__global__ __launch_bounds__(256) void k6_kernel(
        const float* __restrict__ h2, const float* __restrict__ fcwT,
        const float* __restrict__ fcb, const int* __restrict__ lengths,
        float* __restrict__ out_preds, int t) {
    int w = blockIdx.x * 4 + (threadIdx.x >> 6);  // [0, 32*275)
    int lane = threadIdx.x & 63;
    int bg = w / Vn, v = w - bg * Vn;
    const float* row = fcwT + (size_t)v * Dn;
    float4 hv[4][2];
#pragma unroll
    for (int i = 0; i < 4; i++) {
        const float* hb = h2 + (bg * 4 + i) * Dn;
        hv[i][0] = *(const float4*)(hb + 4 * lane);
        hv[i][1] = *(const float4*)(hb + 4 * lane + 256);
    }
    float acc[4] = {0.f, 0.f, 0.f, 0.f};
#pragma unroll
    for (int c = 0; c < 2; c++) {
        float4 wv = *(const float4*)(row + 4 * lane + 256 * c);
#pragma unroll
        for (int i = 0; i < 4; i++)
            acc[i] += hv[i][c].x * wv.x + hv[i][c].y * wv.y + hv[i][c].z * wv.z + hv[i][c].w * wv.w;
    }
#pragma unroll
    for (int o = 32; o > 0; o >>= 1) {
#pragma unroll
        for (int i = 0; i < 4; i++) acc[i] += __shfl_xor(acc[i], o, 64);
    }
    if (lane == 0) {
        float bias = fcb[v];
#pragma unroll
        for (int i = 0; i < 4; i++) {
            int b = bg * 4 + i;
            int dec = lengths[b] - 1;
            out_preds[((size_t)b * TM1 + t) * Vn + v] = (t < dec) ? (acc[i] + bias) : 0.f;
        }
    }
}

extern "C" void kernel_launch(void* const* d_in, const int* in_sizes, int n_in,
                              void* d_out, int out_size, void* d_ws, size_t ws_size,
                              hipStream_t stream) {
    const float* feats    = (const float*)d_in[0];
    const int*   captions = (const int*)d_in[1];
    const int*   lengths  = (const int*)d_in[2];
    const float* U_w      = (const float*)d_in[3];
    const float* U_b      = (const float*)d_in[4];
    const float* W_w      = (const float*)d_in[5];
    const float* W_b      = (const float*)d_in[6];
    const float* v_w      = (const float*)d_in[7];
    const float* v_b      = (const float*)d_in[8];
    const float* init_h_w = (const float*)d_in[9];
    const float* init_h_b = (const float*)d_in[10];
    const float* init_c_w = (const float*)d_in[11];
    const float* init_c_b = (const float*)d_in[12];
    const float* f_beta_w = (const float*)d_in[13];
    const float* f_beta_b = (const float*)d_in[14];
    const float* fc_w     = (const float*)d_in[15];
    const float* fc_b     = (const float*)d_in[16];
    const float* emb      = (const float*)d_in[17];
    const float* lstm_w_ih = (const float*)d_in[18];
    const float* lstm_w_hh = (const float*)d_in[19];
    const float* lstm_b_ih = (const float*)d_in[20];
    const float* lstm_b_hh = (const float*)d_in[21];

    float* ws    = (float*)d_ws;
    float* Ws    = ws;                                  // B*P*D = 37,748,736
    float* mean  = Ws + (size_t)Bn * Pn * Dn;           // B*E
    float* hA    = mean + Bn * En;                      // B*D
    float* hB    = hA + Bn * Dn;
    float* cbuf  = hB + Bn * Dn;
    float* hU    = cbuf + Bn * Dn;
    float* gate  = hU + Bn * Dn;                        // B*E
    float* esc   = gate + Bn * En;                      // B*P
    float* alpha = esc + Bn * Pn;
    float* xctx  = alpha + Bn * Pn;                     // B*E
    float* gbuf  = xctx + Bn * En;                      // B*4D
    float* UwT   = gbuf + (size_t)Bn * 4 * Dn;          // D*D
    float* fbwT  = UwT + Dn * Dn;                       // D*E
    float* fcwT  = fbwT + Dn * En;                      // D*V

    float* out_preds  = (float*)d_out;
    float* out_alphas = out_preds + (size_t)Bn * TM1 * Vn;
    float* out_declen = out_alphas + (size_t)Bn * TM1 * Pn;

    // ---- one-time (per call) precompute ----
    mean_kernel<<<Bn * En / 4, 256, 0, stream>>>(feats, mean);
    init_kernel<<<Bn, 512, 0, stream>>>(mean, init_h_w, init_h_b, init_c_w, init_c_b, hA, cbuf);
    ws_kernel<<<dim3(Pn, Bn), 512, 0, stream>>>(feats, W_w, W_b, Ws);
    declen_kernel<<<1, 128, 0, stream>>>(lengths, out_declen);
    transpose_kernel<<<(Dn * Dn + 255) / 256, 256, 0, stream>>>(U_w, UwT, Dn, Dn);
    transpose_kernel<<<(Dn * En + 255) / 256, 256, 0, stream>>>(f_beta_w, fbwT, Dn, En);
    transpose_kernel<<<(Dn * Vn + 255) / 256, 256, 0, stream>>>(fc_w, fcwT, Dn, Vn);

    // ---- recurrent loop ----
    for (int t = 0; t < TM1; t++) {
        const float* hin = (t & 1) ? hB : hA;
        float* hout = (t & 1) ? hA : hB;
        k1_kernel<<<32 * 1024 / 4, 256, 0, stream>>>(hin, UwT, U_b, fbwT, f_beta_b, hU, gate);
        k2_kernel<<<Bn * Pn / 4, 256, 0, stream>>>(Ws, hU, v_w, v_b, esc);
        k3_kernel<<<Bn, Pn, 0, stream>>>(esc, alpha, out_alphas, lengths, t);
        k4_kernel<<<Bn * En / 4, 256, 0, stream>>>(feats, alpha, gate, xctx);
        k5_kernel<<<32 * 2048 / 4, 256, 0, stream>>>(hin, xctx, emb, captions,
                                                     lstm_w_ih, lstm_w_hh, lstm_b_ih, lstm_b_hh,
                                                     gbuf, t);
        k5b_kernel<<<Bn * Dn / 256, 256, 0, stream>>>(gbuf, hout, cbuf);
        k6_kernel<<<32 * Vn / 4, 256, 0, stream>>>(hout, fcwT, fc_b, lengths, out_preds, t);
    }
}

// Round 2
// 31957.080 us; speedup vs baseline: 1.4162x; 1.4162x over previous
//
#include <hip/hip_runtime.h>
#include <math.h>

// B=128, E=512, D=512, V=275, HW=24 -> P=576, T=300
static constexpr int Bn  = 128;
static constexpr int En  = 512;
static constexpr int Dn  = 512;
static constexpr int Vn  = 275;
static constexpr int Pn  = 576;
static constexpr int Tn  = 300;
static constexpr int TM1 = 299;

typedef unsigned short ushort_t;
typedef unsigned int uint_t;

__device__ __forceinline__ float fast_tanh(float x) {
    float e2 = __expf(2.0f * x);
    return 1.0f - 2.0f / (e2 + 1.0f);
}
__device__ __forceinline__ float sigmoidf_(float x) {
    return 1.0f / (1.0f + __expf(-x));
}
__device__ __forceinline__ float wave_reduce(float v) {
#pragma unroll
    for (int o = 32; o > 0; o >>= 1) v += __shfl_xor(v, o, 64);
    return v;
}
__device__ __forceinline__ ushort_t f2b(float x) {      // fp32 -> bf16 RNE
    uint_t u = __float_as_uint(x);
    u = (u + 0x7fffu + ((u >> 16) & 1u)) >> 16;
    return (ushort_t)u;
}
__device__ __forceinline__ float b2f(ushort_t u) {
    return __uint_as_float(((uint_t)u) << 16);
}
__device__ __forceinline__ void unpack8(uint4 q, float* f) {  // 8 bf16 (little-endian pairs)
    f[0] = __uint_as_float(q.x << 16); f[1] = __uint_as_float(q.x & 0xffff0000u);
    f[2] = __uint_as_float(q.y << 16); f[3] = __uint_as_float(q.y & 0xffff0000u);
    f[4] = __uint_as_float(q.z << 16); f[5] = __uint_as_float(q.z & 0xffff0000u);
    f[6] = __uint_as_float(q.w << 16); f[7] = __uint_as_float(q.w & 0xffff0000u);
}

// ---------------- one-time kernels ----------------

__global__ void mean_kernel(const float* __restrict__ feats, float* __restrict__ mean) {
    int w = blockIdx.x * 4 + (threadIdx.x >> 6);   // row in [0, B*E)
    int lane = threadIdx.x & 63;
    const float* row = feats + (size_t)w * Pn;
    float s = 0.f;
#pragma unroll
    for (int i = 0; i < 9; i++) s += row[lane + i * 64];
    s = wave_reduce(s);
    if (lane == 0) mean[w] = s * (1.0f / Pn);
}

__global__ void init_kernel(const float* __restrict__ mean,
                            const float* __restrict__ ihw, const float* __restrict__ ihb,
                            const float* __restrict__ icw, const float* __restrict__ icb,
                            float* __restrict__ h, float* __restrict__ c) {
    int b = blockIdx.x; int d = threadIdx.x;  // 512 threads
    const float* m = mean + b * En;
    float ah = ihb[d], ac = icb[d];
#pragma unroll 8
    for (int e = 0; e < En; e++) {
        float mv = m[e];
        ah += mv * ihw[e * Dn + d];
        ac += mv * icw[e * Dn + d];
    }
    h[b * Dn + d] = ah;
    c[b * Dn + d] = ac;
}

// Ws[b,p,d] = sum_e feats[b,e,p] * W_w[e,d] + W_b[d]  -> bf16
__global__ void ws_kernel(const float* __restrict__ feats, const float* __restrict__ Ww,
                          const float* __restrict__ Wb, ushort_t* __restrict__ WsH) {
    int p = blockIdx.x, b = blockIdx.y, d = threadIdx.x;  // 512 threads
    const float* f = feats + (size_t)b * En * Pn + p;
    float acc = Wb[d];
#pragma unroll 8
    for (int e = 0; e < En; e++) acc += f[(size_t)e * Pn] * Ww[e * Dn + d];
    WsH[((size_t)b * Pn + p) * Dn + d] = f2b(acc);
}

__global__ void declen_kernel(const int* __restrict__ lengths, float* __restrict__ out_declen) {
    int b = threadIdx.x;
    if (b < Bn) out_declen[b] = (float)(lengths[b] - 1);
}

// fp32 -> bf16 straight copy
__global__ void cvt_kernel(const float* __restrict__ src, ushort_t* __restrict__ dst, int n) {
    int idx = blockIdx.x * 256 + threadIdx.x;
    if (idx < n) dst[idx] = f2b(src[idx]);
}

// transpose + cvt: src[rows][cols] fp32 -> dst[cols][rows] bf16
__global__ void cvtT_kernel(const float* __restrict__ src, ushort_t* __restrict__ dst,
                            int rows, int cols) {
    int idx = blockIdx.x * 256 + threadIdx.x;
    if (idx >= rows * cols) return;
    int r = idx / cols, c = idx - r * cols;
    dst[(size_t)c * rows + r] = f2b(src[idx]);
}

// ---------------- per-step kernels ----------------

// Fused k1+k6: per wave = (bgroup-of-4, jgroup-of-4). j<512: hU; j<1024: gate; else preds(t=tau-1).
__global__ __launch_bounds__(256) void k16_kernel(
        const float* __restrict__ h,
        const ushort_t* __restrict__ UwTh, const float* __restrict__ Ub,
        const ushort_t* __restrict__ fbwTh, const float* __restrict__ fbb,
        const ushort_t* __restrict__ fcwTh, const float* __restrict__ fcb,
        const int* __restrict__ lengths,
        float* __restrict__ hU, float* __restrict__ gate,
        float* __restrict__ out_preds, int tau) {
    int wid = blockIdx.x * 4 + (threadIdx.x >> 6);   // [0, 32*325)
    int lane = threadIdx.x & 63;
    int bg = wid / 325, jg = wid - bg * 325;
    int j0 = jg * 4;
    if (tau == 0 && j0 >= 1024) return;   // no preds at first iteration
    const float4* h4 = (const float4*)h;
    float4 hv[4][2];
#pragma unroll
    for (int i = 0; i < 4; i++) {
        int base = (bg * 4 + i) * 128 + 2 * lane;
        hv[i][0] = h4[base]; hv[i][1] = h4[base + 1];
    }
#pragma unroll
    for (int jj = 0; jj < 4; jj++) {
        int j = j0 + jj;
        const ushort_t* row;
        if (j < 512) row = UwTh + (size_t)j * 512;
        else if (j < 1024) row = fbwTh + (size_t)(j - 512) * 512;
        else { if (j - 1024 >= Vn) continue; row = fcwTh + (size_t)(j - 1024) * 512; }
        uint4 q = *(const uint4*)(row + 8 * lane);
        float w8[8]; unpack8(q, w8);
        float a[4];
#pragma unroll
        for (int i = 0; i < 4; i++) {
            a[i] = hv[i][0].x * w8[0] + hv[i][0].y * w8[1] + hv[i][0].z * w8[2] + hv[i][0].w * w8[3]
                 + hv[i][1].x * w8[4] + hv[i][1].y * w8[5] + hv[i][1].z * w8[6] + hv[i][1].w * w8[7];
        }
#pragma unroll
        for (int o = 32; o > 0; o >>= 1) {
#pragma unroll
            for (int i = 0; i < 4; i++) a[i] += __shfl_xor(a[i], o, 64);
        }
        if (lane == 0) {
            if (j < 512) {
                float bias = Ub[j];
#pragma unroll
                for (int i = 0; i < 4; i++) hU[(bg * 4 + i) * Dn + j] = a[i] + bias;
            } else if (j < 1024) {
                int e = j - 512;
                float bias = fbb[e];
#pragma unroll
                for (int i = 0; i < 4; i++) gate[(bg * 4 + i) * En + e] = sigmoidf_(a[i] + bias);
            } else if (tau > 0) {
                int v = j - 1024;
                int t = tau - 1;
                float bias = fcb[v];
#pragma unroll
                for (int i = 0; i < 4; i++) {
                    int b = bg * 4 + i;
                    int dec = lengths[b] - 1;
                    out_preds[((size_t)b * TM1 + t) * Vn + v] = (t < dec) ? (a[i] + bias) : 0.f;
                }
            }
        }
    }
}

// e[b,p] = sum_d tanh(WsH[b,p,d] + hU[b,d]) * v_w[d] + v_b   (wave per (b,p))
__global__ __launch_bounds__(256) void k2_kernel(
        const ushort_t* __restrict__ WsH, const float* __restrict__ hU,
        const float* __restrict__ vw, const float* __restrict__ vb,
        float* __restrict__ esc) {
    int wid = blockIdx.x * 4 + (threadIdx.x >> 6);  // [0, B*P)
    int lane = threadIdx.x & 63;
    int b = wid / Pn;
    const ushort_t* row = WsH + (size_t)wid * Dn;
    uint4 q = *(const uint4*)(row + 8 * lane);
    float w8[8]; unpack8(q, w8);
    const float4* hu4 = (const float4*)(hU + (b << 9));
    float4 h0 = hu4[2 * lane], h1 = hu4[2 * lane + 1];
    const float4* v4 = (const float4*)vw;
    float4 v0 = v4[2 * lane], v1 = v4[2 * lane + 1];
    float acc;
    acc  = fast_tanh(w8[0] + h0.x) * v0.x;
    acc += fast_tanh(w8[1] + h0.y) * v0.y;
    acc += fast_tanh(w8[2] + h0.z) * v0.z;
    acc += fast_tanh(w8[3] + h0.w) * v0.w;
    acc += fast_tanh(w8[4] + h1.x) * v1.x;
    acc += fast_tanh(w8[5] + h1.y) * v1.y;
    acc += fast_tanh(w8[6] + h1.z) * v1.z;
    acc += fast_tanh(w8[7] + h1.w) * v1.w;
    acc = wave_reduce(acc);
    if (lane == 0) esc[wid] = acc + vb[0];
}

// softmax over P per b
__global__ void k3_kernel(const float* __restrict__ esc, float* __restrict__ alpha,
                          float* __restrict__ out_alphas, const int* __restrict__ lengths, int t) {
    __shared__ float red[16];
    int b = blockIdx.x, tid = threadIdx.x;   // 576 threads
    int wid = tid >> 6, lane = tid & 63;
    float v = esc[b * Pn + tid];
    float m = v;
#pragma unroll
    for (int o = 32; o > 0; o >>= 1) m = fmaxf(m, __shfl_xor(m, o, 64));
    if (lane == 0) red[wid] = m;
    __syncthreads();
    if (tid == 0) {
        float mm = red[0];
        for (int i = 1; i < 9; i++) mm = fmaxf(mm, red[i]);
        red[9] = mm;
    }
    __syncthreads();
    float mx = red[9];
    float ex = __expf(v - mx);
    float s = ex;
#pragma unroll
    for (int o = 32; o > 0; o >>= 1) s += __shfl_xor(s, o, 64);
    if (lane == 0) red[wid] = s;
    __syncthreads();
    if (tid == 0) {
        float ss = 0.f;
        for (int i = 0; i < 9; i++) ss += red[i];
        red[10] = ss;
    }
    __syncthreads();
    float a = ex / red[10];
    alpha[b * Pn + tid] = a;
    int dec = lengths[b] - 1;
    out_alphas[((size_t)b * TM1 + t) * Pn + tid] = (t < dec) ? a : 0.f;
}

// xctx[b,e] = gate[b,e] * sum_p alpha[b,p] * featsH[b,e,p]   (wave per (b,e) row)
__global__ __launch_bounds__(256) void k4_kernel(
        const ushort_t* __restrict__ featsH, const float* __restrict__ alpha,
        const float* __restrict__ gate, float* __restrict__ xctx) {
    int wid = blockIdx.x * 4 + (threadIdx.x >> 6);  // [0, B*E)
    int lane = threadIdx.x & 63;
    int b = wid >> 9;
    const ushort_t* f = featsH + (size_t)wid * Pn;
    const float* al = alpha + b * Pn;
    uint4 q = *(const uint4*)(f + 8 * lane);
    float w8[8]; unpack8(q, w8);
    const float4* a4 = (const float4*)al;
    float4 a0 = a4[2 * lane], a1 = a4[2 * lane + 1];
    float s;
    s  = w8[0] * a0.x + w8[1] * a0.y + w8[2] * a0.z + w8[3] * a0.w;
    s += w8[4] * a1.x + w8[5] * a1.y + w8[6] * a1.z + w8[7] * a1.w;
    s += b2f(f[512 + lane]) * al[512 + lane];   // tail 64
    s = wave_reduce(s);
    if (lane == 0) xctx[wid] = gate[wid] * s;
}

// Fused LSTM: wave = (bgroup-of-4, d). Computes all 4 gate rows {d,512+d,1024+d,1536+d},
// then the pointwise update -> writes c and h2 directly.
__global__ __launch_bounds__(256) void k5_kernel(
        const float* __restrict__ h, const float* __restrict__ xctx,
        const float* __restrict__ emb, const int* __restrict__ captions,
        const ushort_t* __restrict__ wihH, const ushort_t* __restrict__ whhH,
        const float* __restrict__ bih, const float* __restrict__ bhh,
        float* __restrict__ c, float* __restrict__ h2, int tau) {
    int wid = blockIdx.x * 4 + (threadIdx.x >> 6);  // [0, 32*512)
    int lane = threadIdx.x & 63;
    int bg = wid >> 9, d = wid & 511;
    float4 u[4][6];   // per batch: emb0,emb1, gctx0,gctx1, h0,h1
#pragma unroll
    for (int i = 0; i < 4; i++) {
        int b = bg * 4 + i;
        int tok = captions[b * Tn + tau];
        const float4* e4 = (const float4*)(emb + (size_t)tok * Dn);
        const float4* x4 = (const float4*)(xctx + b * En);
        const float4* h4 = (const float4*)(h + b * Dn);
        u[i][0] = e4[2 * lane]; u[i][1] = e4[2 * lane + 1];
        u[i][2] = x4[2 * lane]; u[i][3] = x4[2 * lane + 1];
        u[i][4] = h4[2 * lane]; u[i][5] = h4[2 * lane + 1];
    }
    float acc[4][4];
#pragma unroll
    for (int g = 0; g < 4; g++)
#pragma unroll
        for (int i = 0; i < 4; i++) acc[g][i] = 0.f;
#pragma unroll
    for (int g = 0; g < 4; g++) {
        int j = g * 512 + d;
        const ushort_t* wi = wihH + (size_t)j * 1024;
        const ushort_t* wh = whhH + (size_t)j * 512;
        uint4 q0 = *(const uint4*)(wi + 8 * lane);
        uint4 q1 = *(const uint4*)(wi + 512 + 8 * lane);
        uint4 q2 = *(const uint4*)(wh + 8 * lane);
        float wa[8], wb[8], wc[8];
        unpack8(q0, wa); unpack8(q1, wb); unpack8(q2, wc);
#pragma unroll
        for (int i = 0; i < 4; i++) {
            float s;
            s  = u[i][0].x * wa[0] + u[i][0].y * wa[1] + u[i][0].z * wa[2] + u[i][0].w * wa[3];
            s += u[i][1].x * wa[4] + u[i][1].y * wa[5] + u[i][1].z * wa[6] + u[i][1].w * wa[7];
            s += u[i][2].x * wb[0] + u[i][2].y * wb[1] + u[i][2].z * wb[2] + u[i][2].w * wb[3];
            s += u[i][3].x * wb[4] + u[i][3].y * wb[5] + u[i][3].z * wb[6] + u[i][3].w * wb[7];
            s += u[i][4].x * wc[0] + u[i][4].y * wc[1] + u[i][4].z * wc[2] + u[i][4].w * wc[3];
            s += u[i][5].x * wc[4] + u[i][5].y * wc[5] + u[i][5].z * wc[6] + u[i][5].w * wc[7];
            acc[g][i] += s;
        }
    }
#pragma unroll
    for (int o = 32; o > 0; o >>= 1) {
#pragma unroll
        for (int g = 0; g < 4; g++)
#pragma unroll
            for (int i = 0; i < 4; i++) acc[g][i] += __shfl_xor(acc[g][i], o, 64);
    }
    if (lane == 0) {
        float bi = bih[d] + bhh[d];
        float bf = bih[512 + d] + bhh[512 + d];
        float bgg = bih[1024 + d] + bhh[1024 + d];
        float bo = bih[1536 + d] + bhh[1536 + d];
#pragma unroll
        for (int i = 0; i < 4; i++) {
            int b = bg * 4 + i;
            float ig = sigmoidf_(acc[0][i] + bi);
            float fg = sigmoidf_(acc[1][i] + bf);
            float gg = fast_tanh(acc[2][i] + bgg);
            float og = sigmoidf_(acc[3][i] + bo);
            float cn = fg * c[b * Dn + d] + ig * gg;
            c[b * Dn + d] = cn;
            h2[b * Dn + d] = og * fast_tanh(cn);
        }
    }
}

extern "C" void kernel_launch(void* const* d_in, const int* in_sizes, int n_in,
                              void* d_out, int out_size, void* d_ws, size_t ws_size,
                              hipStream_t stream) {
    const float* feats    = (const float*)d_in[0];
    const int*   captions = (const int*)d_in[1];
    const int*   lengths  = (const int*)d_in[2];
    const float* U_w      = (const float*)d_in[3];
    const float* U_b      = (const float*)d_in[4];
    const float* W_w      = (const float*)d_in[5];
    const float* W_b      = (const float*)d_in[6];
    const float* v_w      = (const float*)d_in[7];
    const float* v_b      = (const float*)d_in[8];
    const float* init_h_w = (const float*)d_in[9];
    const float* init_h_b = (const float*)d_in[10];
    const float* init_c_w = (const float*)d_in[11];
    const float* init_c_b = (const float*)d_in[12];
    const float* f_beta_w = (const float*)d_in[13];
    const float* f_beta_b = (const float*)d_in[14];
    const float* fc_w     = (const float*)d_in[15];
    const float* fc_b     = (const float*)d_in[16];
    const float* emb      = (const float*)d_in[17];
    const float* lstm_w_ih = (const float*)d_in[18];
    const float* lstm_w_hh = (const float*)d_in[19];
    const float* lstm_b_ih = (const float*)d_in[20];
    const float* lstm_b_hh = (const float*)d_in[21];

    char* base = (char*)d_ws;
    size_t off = 0;
    ushort_t* WsH    = (ushort_t*)(base + off); off += (size_t)Bn * Pn * Dn * 2;   // 75.5 MB
    ushort_t* featsH = (ushort_t*)(base + off); off += (size_t)Bn * En * Pn * 2;   // 75.5 MB
    ushort_t* wihH   = (ushort_t*)(base + off); off += (size_t)4 * Dn * (Dn + En) * 2;
    ushort_t* whhH   = (ushort_t*)(base + off); off += (size_t)4 * Dn * Dn * 2;
    ushort_t* UwTh   = (ushort_t*)(base + off); off += (size_t)Dn * Dn * 2;
    ushort_t* fbwTh  = (ushort_t*)(base + off); off += (size_t)En * Dn * 2;
    ushort_t* fcwTh  = (ushort_t*)(base + off); off += (size_t)Vn * Dn * 2;
    float* mean  = (float*)(base + off); off += (size_t)Bn * En * 4;
    float* hA    = (float*)(base + off); off += (size_t)Bn * Dn * 4;
    float* hB    = (float*)(base + off); off += (size_t)Bn * Dn * 4;
    float* cbuf  = (float*)(base + off); off += (size_t)Bn * Dn * 4;
    float* hU    = (float*)(base + off); off += (size_t)Bn * Dn * 4;
    float* gate  = (float*)(base + off); off += (size_t)Bn * En * 4;
    float* xctx  = (float*)(base + off); off += (size_t)Bn * En * 4;
    float* esc   = (float*)(base + off); off += (size_t)Bn * Pn * 4;
    float* alpha = (float*)(base + off); off += (size_t)Bn * Pn * 4;

    float* out_preds  = (float*)d_out;
    float* out_alphas = out_preds + (size_t)Bn * TM1 * Vn;
    float* out_declen = out_alphas + (size_t)Bn * TM1 * Pn;

    // ---- one-time precompute ----
    mean_kernel<<<Bn * En / 4, 256, 0, stream>>>(feats, mean);
    init_kernel<<<Bn, 512, 0, stream>>>(mean, init_h_w, init_h_b, init_c_w, init_c_b, hA, cbuf);
    ws_kernel<<<dim3(Pn, Bn), 512, 0, stream>>>(feats, W_w, W_b, WsH);
    declen_kernel<<<1, 128, 0, stream>>>(lengths, out_declen);
    {
        int n = Bn * En * Pn;
        cvt_kernel<<<(n + 255) / 256, 256, 0, stream>>>(feats, featsH, n);
    }
    cvt_kernel<<<(4 * Dn * (Dn + En) + 255) / 256, 256, 0, stream>>>(lstm_w_ih, wihH, 4 * Dn * (Dn + En));
    cvt_kernel<<<(4 * Dn * Dn + 255) / 256, 256, 0, stream>>>(lstm_w_hh, whhH, 4 * Dn * Dn);
    cvtT_kernel<<<(Dn * Dn + 255) / 256, 256, 0, stream>>>(U_w, UwTh, Dn, Dn);
    cvtT_kernel<<<(Dn * En + 255) / 256, 256, 0, stream>>>(f_beta_w, fbwTh, Dn, En);
    cvtT_kernel<<<(Dn * Vn + 255) / 256, 256, 0, stream>>>(fc_w, fcwTh, Dn, Vn);

    // ---- recurrent loop: 5 kernels per step ----
    const int k16_blocks = 32 * 325 / 4;   // 2600
    for (int tau = 0; tau < TM1; tau++) {
        const float* hin = (tau & 1) ? hB : hA;
        float* hout = (tau & 1) ? hA : hB;
        k16_kernel<<<k16_blocks, 256, 0, stream>>>(hin, UwTh, U_b, fbwTh, f_beta_b,
                                                   fcwTh, fc_b, lengths, hU, gate,
                                                   out_preds, tau);
        k2_kernel<<<Bn * Pn / 4, 256, 0, stream>>>(WsH, hU, v_w, v_b, esc);
        k3_kernel<<<Bn, Pn, 0, stream>>>(esc, alpha, out_alphas, lengths, tau);
        k4_kernel<<<Bn * En / 4, 256, 0, stream>>>(featsH, alpha, gate, xctx);
        k5_kernel<<<32 * 512 / 4, 256, 0, stream>>>(hin, xctx, emb, captions,
                                                    wihH, whhH, lstm_b_ih, lstm_b_hh,
                                                    cbuf, hout, tau);
    }
    // final fused launch emits preds for t = TM1-1 (reads h from the last step)
    k16_kernel<<<k16_blocks, 256, 0, stream>>>((TM1 & 1) ? hB : hA, UwTh, U_b, fbwTh, f_beta_b,
                                               fcwTh, fc_b, lengths, hU, gate,
                                               out_preds, TM1);
}